// Round 1
// baseline (3015.613 us; speedup 1.0000x reference)
//
#include <hip/hip_runtime.h>

#define NCAM 6
#define DD 118
#define FHH 32
#define FWW 88
#define CC 80
#define NXV 360
#define NYV 360
#define PTS_PER_CAM (DD * FHH * FWW)          /* 332288 */
#define BLK 256
#define BLOCKS_PER_CAM (PTS_PER_CAM / BLK)    /* 1298, exact */

// inverse of row-major 3x3 in double
__device__ __forceinline__ void inv3x3d(const double* m, double* inv) {
    double c00 = m[4] * m[8] - m[5] * m[7];
    double c01 = m[3] * m[8] - m[5] * m[6];
    double c02 = m[3] * m[7] - m[4] * m[6];
    double det = m[0] * c00 - m[1] * c01 + m[2] * c02;
    double id  = 1.0 / det;
    inv[0] =  c00 * id;
    inv[1] = (m[2] * m[7] - m[1] * m[8]) * id;
    inv[2] = (m[1] * m[5] - m[2] * m[4]) * id;
    inv[3] = -c01 * id;
    inv[4] = (m[0] * m[8] - m[2] * m[6]) * id;
    inv[5] = (m[2] * m[3] - m[0] * m[5]) * id;
    inv[6] =  c02 * id;
    inv[7] = (m[1] * m[6] - m[0] * m[7]) * id;
    inv[8] = (m[0] * m[4] - m[1] * m[3]) * id;
}

// Per-camera parameter pack, 48 floats:
// [0:9)  A  = inv(post_rots)
// [9:12) t1 = post_trans
// [12:21) Cm = rots @ inv(intrins)
// [21:24) t2 = trans
// [24:27) l2e_t
// [27:36) L  = inv(l2e_r)
// [36:45) E  = er
// [45:48) et
__global__ void precomp_kernel(const float* __restrict__ c2e,
                               const float* __restrict__ l2e,
                               const float* __restrict__ intr,
                               const float* __restrict__ aug,
                               const float* __restrict__ laug,
                               float* __restrict__ P) {
    int n = threadIdx.x;
    if (n >= NCAM) return;
    double rots[9], intrins[9], post[9], l2er[9], er[9];
    double trans[3], ptrans[3], l2et[3], et[3];
    for (int i = 0; i < 3; i++) {
        for (int j = 0; j < 3; j++) {
            rots[i * 3 + j]    = c2e[n * 16 + i * 4 + j];
            intrins[i * 3 + j] = intr[n * 16 + i * 4 + j];
            post[i * 3 + j]    = aug[n * 16 + i * 4 + j];
            l2er[i * 3 + j]    = l2e[i * 4 + j];
            er[i * 3 + j]      = laug[i * 4 + j];
        }
        trans[i]  = c2e[n * 16 + i * 4 + 3];
        ptrans[i] = aug[n * 16 + i * 4 + 3];
        l2et[i]   = l2e[i * 4 + 3];
        et[i]     = laug[i * 4 + 3];
    }
    double A[9], IC[9], L[9], Cm[9];
    inv3x3d(post, A);
    inv3x3d(intrins, IC);
    inv3x3d(l2er, L);
    for (int i = 0; i < 3; i++)
        for (int j = 0; j < 3; j++)
            Cm[i * 3 + j] = rots[i * 3 + 0] * IC[0 + j] +
                            rots[i * 3 + 1] * IC[3 + j] +
                            rots[i * 3 + 2] * IC[6 + j];
    float* p = P + n * 48;
    for (int k = 0; k < 9; k++) p[k]      = (float)A[k];
    for (int k = 0; k < 3; k++) p[9 + k]  = (float)ptrans[k];
    for (int k = 0; k < 9; k++) p[12 + k] = (float)Cm[k];
    for (int k = 0; k < 3; k++) p[21 + k] = (float)trans[k];
    for (int k = 0; k < 3; k++) p[24 + k] = (float)l2et[k];
    for (int k = 0; k < 9; k++) p[27 + k] = (float)L[k];
    for (int k = 0; k < 9; k++) p[36 + k] = (float)er[k];
    for (int k = 0; k < 3; k++) p[45 + k] = (float)et[k];
}

__global__ __launch_bounds__(BLK) void scatter_kernel(
        const float* __restrict__ feats,
        const float* __restrict__ P,
        float* __restrict__ out) {
    int cam   = blockIdx.x / BLOCKS_PER_CAM;          // wave-uniform
    int local = (blockIdx.x % BLOCKS_PER_CAM) * BLK + threadIdx.x;
    int d   = local / (FHH * FWW);
    int rem = local - d * (FHH * FWW);
    int h   = rem / FWW;
    int w   = rem - h * FWW;

    const float* p = P + cam * 48;

    // frustum point (image-aug space); linspace steps computed in double then cast
    float fx = (float)((double)w * (703.0 / 87.0));   // linspace(0, 703, 88)
    float fy = (float)((double)h * (255.0 / 31.0));   // linspace(0, 255, 32)
    float fd = 1.0f + 0.5f * (float)d;                // arange(1, 60, 0.5)

    // undo image augmentation
    float vx = fx - p[9], vy = fy - p[10], vz = fd - p[11];
    float qx = p[0] * vx + p[1] * vy + p[2] * vz;
    float qy = p[3] * vx + p[4] * vy + p[5] * vz;
    float qz = p[6] * vx + p[7] * vy + p[8] * vz;
    // un-project: (u*z, v*z, z)
    float px = qx * qz, py = qy * qz, pz = qz;
    // cam -> ego
    float rx = p[12] * px + p[13] * py + p[14] * pz + p[21];
    float ry = p[15] * px + p[16] * py + p[17] * pz + p[22];
    float rz = p[18] * px + p[19] * py + p[20] * pz + p[23];
    // ego -> lidar
    rx -= p[24]; ry -= p[25]; rz -= p[26];
    float sx = p[27] * rx + p[28] * ry + p[29] * rz;
    float sy = p[30] * rx + p[31] * ry + p[32] * rz;
    float sz = p[33] * rx + p[34] * ry + p[35] * rz;
    // lidar aug
    float gx = p[36] * sx + p[37] * sy + p[38] * sz + p[45];
    float gy = p[39] * sx + p[40] * sy + p[41] * sz + p[46];
    float gz = p[42] * sx + p[43] * sy + p[44] * sz + p[47];

    // replicate reference's f32 rounding of (bx - dx/2)
    const float offx = (-54.0f + 0.15f) - 0.15f;
    const float offy = (-54.0f + 0.15f) - 0.15f;
    const float offz = -10.0f;

    int cx = (int)((gx - offx) / 0.3f);    // trunc-toward-zero, saturating cvt
    int cy = (int)((gy - offy) / 0.3f);
    int cz = (int)((gz - offz) / 20.0f);

    bool kept = (cx >= 0) & (cx < NXV) & (cy >= 0) & (cy < NYV) &
                (cz >= 0) & (cz < 1);
    if (!kept) return;

    size_t pt = (size_t)cam * PTS_PER_CAM + (size_t)local;
    const float4* row = (const float4*)(feats + pt * CC);
    float* outp = out + (size_t)cx * NYV + cy;   // + c*NXV*NYV per channel
    #pragma unroll
    for (int c4 = 0; c4 < CC / 4; ++c4) {
        float4 v = row[c4];
        atomicAdd(outp + (size_t)(4 * c4 + 0) * (NXV * NYV), v.x);
        atomicAdd(outp + (size_t)(4 * c4 + 1) * (NXV * NYV), v.y);
        atomicAdd(outp + (size_t)(4 * c4 + 2) * (NXV * NYV), v.z);
        atomicAdd(outp + (size_t)(4 * c4 + 3) * (NXV * NYV), v.w);
    }
}

extern "C" void kernel_launch(void* const* d_in, const int* in_sizes, int n_in,
                              void* d_out, int out_size, void* d_ws, size_t ws_size,
                              hipStream_t stream) {
    const float* feats = (const float*)d_in[0];
    const float* c2e   = (const float*)d_in[1];
    const float* l2e   = (const float*)d_in[2];
    const float* intr  = (const float*)d_in[3];
    const float* aug   = (const float*)d_in[4];
    const float* laug  = (const float*)d_in[5];
    float* out = (float*)d_out;
    float* P   = (float*)d_ws;   // 6*48 floats = 1152 B

    hipMemsetAsync(d_out, 0, (size_t)out_size * sizeof(float), stream);
    precomp_kernel<<<1, 64, 0, stream>>>(c2e, l2e, intr, aug, laug, P);
    scatter_kernel<<<NCAM * BLOCKS_PER_CAM, BLK, 0, stream>>>(feats, P, out);
}